// Round 13
// baseline (43.631 us; speedup 1.0000x reference)
//
#include <hip/hip_runtime.h>
#include <math.h>

#define N_S 1024
#define XD  768
#define LOW 300
#define KP  320     // f16 k-padding
#define KP2 160     // u32 (h2) per row

typedef _Float16 h2  __attribute__((ext_vector_type(2)));
typedef __fp16   g2  __attribute__((ext_vector_type(2)));
typedef _Float16 v8h __attribute__((ext_vector_type(8)));
typedef float    f4  __attribute__((ext_vector_type(4)));

union U32H2 { unsigned int u; h2 h; };
__device__ inline h2 u2h(unsigned int v){ U32H2 t; t.u = v; return t.h; }
__device__ inline unsigned int pk(float a, float b){
    g2 t = __builtin_amdgcn_cvt_pkrtz(a, b);
    return __builtin_bit_cast(unsigned int, t);
}
union U4V8 { uint4 u; v8h v; };

// ---------------------------------------------------------------------------
// Kernel 1: projection GEMM via MFMA f16 (r11/r12-verified). 320 jobs.
// Also zeroes partsum[1024] and cnt (visible to kernel 2 via stream order).
// ---------------------------------------------------------------------------
__global__ __launch_bounds__(512)
void gemm_h(const float* __restrict__ x, const float* __restrict__ y,
            const float* __restrict__ W1, const float* __restrict__ b1g,
            unsigned int* __restrict__ hx_h, unsigned int* __restrict__ hy_h,
            float* __restrict__ partsum, unsigned int* __restrict__ cnt)
{
    __shared__ unsigned int As[2][32][36];
    __shared__ unsigned int Bs[2][64][36];

    const int tid = threadIdx.x;
    const int job = blockIdx.x;
    if (job < 256 && tid < 4) partsum[job * 4 + tid] = 0.f;
    if (job == 0 && tid == 4) cnt[0] = 0u;

    const int which = job >= 160;
    const int t = which ? job - 160 : job;
    const int n0 = (t % 5) * 64;
    const int r0 = (t / 5) * 32;
    const float* A = which ? y : x;
    const float* W = W1 + (size_t)which * XD * LOW;
    _Float16* outh = (_Float16*)(which ? hy_h : hx_h);

    const int w = tid >> 6, l = tid & 63;
    const int wm = w >> 2, wn = w & 3;         // 2M x 4N
    const int lr = l & 15, lg = l >> 4;

    const int arow = tid >> 4, aq = tid & 15;  // A staging: 32 rows x 16 f4
    const int bn = tid & 63, bms = tid >> 6;   // B staging: 64 ncols x 8 m-grp
    const bool bin = (n0 + bn) < LOW;

    f4 acc = {};
    float4 a0; float bw[8];
    a0 = *(const float4*)&A[(size_t)(r0 + arow) * XD + aq * 4];
    #pragma unroll
    for (int s = 0; s < 8; ++s)
        bw[s] = bin ? W[(size_t)(bms * 8 + s) * LOW + n0 + bn] : 0.f;

    const int NC = XD / 64;                    // 12
    for (int c = 0; c < NC; ++c) {
        const int buf = c & 1;
        *(uint2*)&As[buf][arow][aq * 2] = make_uint2(pk(a0.x, a0.y), pk(a0.z, a0.w));
        *(uint4*)&Bs[buf][bn][bms * 4] =
            uint4{ pk(bw[0],bw[1]), pk(bw[2],bw[3]), pk(bw[4],bw[5]), pk(bw[6],bw[7]) };
        __syncthreads();
        if (c + 1 < NC) {
            const int kb = (c + 1) * 64;
            a0 = *(const float4*)&A[(size_t)(r0 + arow) * XD + kb + aq * 4];
            #pragma unroll
            for (int s = 0; s < 8; ++s)
                bw[s] = bin ? W[(size_t)(kb + bms * 8 + s) * LOW + n0 + bn] : 0.f;
        }
        #pragma unroll
        for (int ks = 0; ks < 2; ++ks) {
            const int ko = ks * 16 + lg * 4;
            U4V8 af; af.u = *(const uint4*)&As[buf][wm * 16 + lr][ko];
            U4V8 bf; bf.u = *(const uint4*)&Bs[buf][wn * 16 + lr][ko];
            acc = __builtin_amdgcn_mfma_f32_16x16x32_f16(af.v, bf.v, acc, 0, 0, 0);
        }
    }

    // D: col = l&15, row = 4*(l>>4)+r  (m89-verified)
    const int col = n0 + wn * 16 + lr;
    const float b1v = (which && col < LOW) ? b1g[col] : 0.f;
    #pragma unroll
    for (int r = 0; r < 4; ++r) {
        const int row = r0 + wm * 16 + lg * 4 + r;
        outh[(size_t)row * KP + col] = (_Float16)(acc[r] + b1v);
    }
}

// ---------------------------------------------------------------------------
// Kernel 2: pairwise critic, TWO j-tiles per block (probe + pipeline).
//   s[i][j] = sum_k relu(hy[i,k]+hx[j,k])*w2[k] + b2
//   partsum[i] += sum_j e^s  (exp(softplus)=1+e^s);  diag[i]=softplus(s[i,i])
// Grid 256 = 32 ib x 8 jp; block: stage Hy once, then for jt=0,1:
// write prefetched Hx regs -> LDS, compute (r9-verified 4i x 4j x k-half
// core), prefetch next tile's Hx during tile-0 compute. Atomic finish (r12).
// ---------------------------------------------------------------------------
__global__ __launch_bounds__(256)
void pair_kernel(const unsigned int* __restrict__ hx_h, const unsigned int* __restrict__ hy_h,
                 const float* __restrict__ W2, const float* __restrict__ b2,
                 float* __restrict__ partsum, float* __restrict__ diag,
                 unsigned int* __restrict__ cnt, float* __restrict__ out)
{
    const int jp = blockIdx.x & 7;     // jb = jp*2 + jt
    const int ib = blockIdx.x >> 3;    // 0..31
    const int i0 = ib * 32;

    __shared__ unsigned int Hy[160][36];   // [kk][i]
    __shared__ unsigned int Hx[160][68];   // [kk][j]
    __shared__ unsigned int w2s[KP2];
    __shared__ unsigned int lastFlag;
    __shared__ float ssum[4];

    const int tid = threadIdx.x;

    // ---- stage Hy once: transpose [i][kk] -> [kk][i] ----
    {
        const int r = tid >> 3, q = tid & 7;
        const unsigned int* src = &hy_h[(size_t)(i0 + r) * KP2];
        #pragma unroll
        for (int e = 0; e < 5; ++e) {
            const int k4 = q + 8 * e;
            uint4 v = *(const uint4*)&src[k4 * 4];
            Hy[k4*4+0][r] = v.x; Hy[k4*4+1][r] = v.y;
            Hy[k4*4+2][r] = v.z; Hy[k4*4+3][r] = v.w;
        }
    }
    if (tid < KP2) {
        int k = tid * 2;
        float w0 = (k < LOW) ? W2[k] : 0.f;
        float w1 = (k + 1 < LOW) ? W2[k + 1] : 0.f;
        w2s[tid] = pk(w0, w1);
    }

    // ---- prefetch tile-0 Hx into registers ----
    const int xr = tid >> 2, xq = tid & 3;
    uint4 xv[10];
    {
        const unsigned int* src = &hx_h[(size_t)(jp * 128 + xr) * KP2];
        #pragma unroll
        for (int e = 0; e < 10; ++e)
            xv[e] = *(const uint4*)&src[(xq + 4 * e) * 4];
    }

    const int tx = tid & 15;           // j = j0 + tx*4 + q
    const int kh = (tid >> 4) & 1;     // k-half
    const int iy = tid >> 5;           // i = i0 + iy*4 + r
    const float b2v = b2[0];
    const h2 hz = h2{(_Float16)0.f, (_Float16)0.f};

    for (int jt = 0; jt < 2; ++jt) {
        const int j0 = (jp * 2 + jt) * 64;
        if (jt) __syncthreads();             // Hx reads of prev tile done
        #pragma unroll
        for (int e = 0; e < 10; ++e) {
            const int k4 = xq + 4 * e;
            Hx[k4*4+0][xr] = xv[e].x; Hx[k4*4+1][xr] = xv[e].y;
            Hx[k4*4+2][xr] = xv[e].z; Hx[k4*4+3][xr] = xv[e].w;
        }
        __syncthreads();
        if (jt == 0) {                       // prefetch tile 1 under compute
            const unsigned int* src = &hx_h[(size_t)(jp * 128 + 64 + xr) * KP2];
            #pragma unroll
            for (int e = 0; e < 10; ++e)
                xv[e] = *(const uint4*)&src[(xq + 4 * e) * 4];
        }

        float acc[4][4] = {};
        const int kbase = kh * 80;
        #pragma unroll 4
        for (int kki = 0; kki < 80; ++kki) {
            const int kk = kbase + kki;
            const uint4 ya = *(const uint4*)&Hy[kk][iy * 4];
            const uint4 xb = *(const uint4*)&Hx[kk][tx * 4];
            const h2 w = u2h(w2s[kk]);
            const unsigned int yar[4] = {ya.x, ya.y, ya.z, ya.w};
            const unsigned int xbr[4] = {xb.x, xb.y, xb.z, xb.w};
            #pragma unroll
            for (int r = 0; r < 4; ++r) {
                const h2 a = u2h(yar[r]);
                #pragma unroll
                for (int q = 0; q < 4; ++q) {
                    h2 z = __builtin_elementwise_max(a + u2h(xbr[q]), hz);
                    acc[r][q] = __builtin_amdgcn_fdot2(z, w, acc[r][q], false);
                }
            }
        }

        // combine k-halves (partner lane differs in bit 4)
        #pragma unroll
        for (int r = 0; r < 4; ++r)
            #pragma unroll
            for (int q = 0; q < 4; ++q)
                acc[r][q] += __shfl_xor(acc[r][q], 16, 64);

        #pragma unroll
        for (int r = 0; r < 4; ++r) {
            const int row = i0 + iy * 4 + r;
            float es = 0.f;
            #pragma unroll
            for (int q = 0; q < 4; ++q) {
                const float s = acc[r][q] + b2v;
                es += __expf(s);
                const int col = j0 + tx * 4 + q;
                if (col == row)
                    atomicExch(&diag[row],
                               fmaxf(s, 0.f) + __logf(1.f + __expf(-fabsf(s))));
            }
            #pragma unroll
            for (int o = 1; o <= 8; o <<= 1) es += __shfl_xor(es, o, 64);
            if ((tid & 31) == 0) atomicAdd(&partsum[row], es);
        }
    }

    // ---- completion: drain atomics, count blocks, last block reduces ----
    asm volatile("s_waitcnt vmcnt(0)" ::: "memory");
    __syncthreads();
    if (tid == 0) lastFlag = (atomicAdd(cnt, 1u) == 255u) ? 1u : 0u;
    __syncthreads();
    if (!lastFlag) return;

    float csum = 0.f;
    #pragma unroll
    for (int g = 0; g < 4; ++g) {
        const int row = g * 256 + tid;
        const float ps = atomicAdd(&partsum[row], 0.f);   // coherent read
        const float dg = atomicAdd(&diag[row], 0.f);      // coherent read
        csum += dg - __logf((float)N_S + ps);
    }
    #pragma unroll
    for (int o = 32; o > 0; o >>= 1) csum += __shfl_xor(csum, o, 64);
    if ((tid & 63) == 0) ssum[tid >> 6] = csum;
    __syncthreads();
    if (tid == 0)
        out[0] = (ssum[0] + ssum[1] + ssum[2] + ssum[3]) * (1.0f / N_S)
               - logf((float)N_S);
}

// ---------------------------------------------------------------------------
extern "C" void kernel_launch(void* const* d_in, const int* in_sizes, int n_in,
                              void* d_out, int out_size, void* d_ws, size_t ws_size,
                              hipStream_t stream)
{
    const float* x  = (const float*)d_in[0];
    const float* y  = (const float*)d_in[1];
    const float* W1 = (const float*)d_in[2];
    const float* b1 = (const float*)d_in[3];
    const float* W2 = (const float*)d_in[4];
    const float* b2 = (const float*)d_in[5];
    float* outp = (float*)d_out;

    unsigned int* hx_h = (unsigned int*)d_ws;             // N_S*KP2 u32
    unsigned int* hy_h = hx_h + (size_t)N_S * KP2;        // N_S*KP2 u32
    float* partsum = (float*)(hy_h + (size_t)N_S * KP2);  // N_S f32
    float* diag = partsum + N_S;                          // N_S f32
    unsigned int* cnt = (unsigned int*)(diag + N_S);      // 1 u32

    gemm_h<<<320, 512, 0, stream>>>(x, y, W1, b1, hx_h, hy_h, partsum, cnt);

    pair_kernel<<<256, 256, 0, stream>>>(hx_h, hy_h, W2, b2,
                                         partsum, diag, cnt, outp);
}

// Round 14
// 41.019 us; speedup vs baseline: 1.0637x; 1.0637x over previous
//
#include <hip/hip_runtime.h>
#include <math.h>

#define N_S 1024
#define XD  768
#define LOW 300
#define KP  320     // f16 k-padding
#define KP2 160     // u32 (h2) per row

typedef _Float16 h2  __attribute__((ext_vector_type(2)));
typedef __fp16   g2  __attribute__((ext_vector_type(2)));
typedef _Float16 v8h __attribute__((ext_vector_type(8)));
typedef float    f4  __attribute__((ext_vector_type(4)));

union U32H2 { unsigned int u; h2 h; };
__device__ inline h2 u2h(unsigned int v){ U32H2 t; t.u = v; return t.h; }
__device__ inline unsigned int pk(float a, float b){
    g2 t = __builtin_amdgcn_cvt_pkrtz(a, b);
    return __builtin_bit_cast(unsigned int, t);
}
union U4V8 { uint4 u; v8h v; };

// ---------------------------------------------------------------------------
// Kernel 1: projection GEMM via MFMA f16 (r11/r12-verified). 320 jobs.
// Also zeroes partsum[1024] and cnt (visible to kernel 2 via stream order).
// ---------------------------------------------------------------------------
__global__ __launch_bounds__(512)
void gemm_h(const float* __restrict__ x, const float* __restrict__ y,
            const float* __restrict__ W1, const float* __restrict__ b1g,
            unsigned int* __restrict__ hx_h, unsigned int* __restrict__ hy_h,
            float* __restrict__ partsum, unsigned int* __restrict__ cnt)
{
    __shared__ unsigned int As[2][32][36];
    __shared__ unsigned int Bs[2][64][36];

    const int tid = threadIdx.x;
    const int job = blockIdx.x;
    if (job < 256 && tid < 4) partsum[job * 4 + tid] = 0.f;
    if (job == 0 && tid == 4) cnt[0] = 0u;

    const int which = job >= 160;
    const int t = which ? job - 160 : job;
    const int n0 = (t % 5) * 64;
    const int r0 = (t / 5) * 32;
    const float* A = which ? y : x;
    const float* W = W1 + (size_t)which * XD * LOW;
    _Float16* outh = (_Float16*)(which ? hy_h : hx_h);

    const int w = tid >> 6, l = tid & 63;
    const int wm = w >> 2, wn = w & 3;         // 2M x 4N
    const int lr = l & 15, lg = l >> 4;

    const int arow = tid >> 4, aq = tid & 15;  // A staging: 32 rows x 16 f4
    const int bn = tid & 63, bms = tid >> 6;   // B staging: 64 ncols x 8 m-grp
    const bool bin = (n0 + bn) < LOW;

    f4 acc = {};
    float4 a0; float bw[8];
    a0 = *(const float4*)&A[(size_t)(r0 + arow) * XD + aq * 4];
    #pragma unroll
    for (int s = 0; s < 8; ++s)
        bw[s] = bin ? W[(size_t)(bms * 8 + s) * LOW + n0 + bn] : 0.f;

    const int NC = XD / 64;                    // 12
    for (int c = 0; c < NC; ++c) {
        const int buf = c & 1;
        *(uint2*)&As[buf][arow][aq * 2] = make_uint2(pk(a0.x, a0.y), pk(a0.z, a0.w));
        *(uint4*)&Bs[buf][bn][bms * 4] =
            uint4{ pk(bw[0],bw[1]), pk(bw[2],bw[3]), pk(bw[4],bw[5]), pk(bw[6],bw[7]) };
        __syncthreads();
        if (c + 1 < NC) {
            const int kb = (c + 1) * 64;
            a0 = *(const float4*)&A[(size_t)(r0 + arow) * XD + kb + aq * 4];
            #pragma unroll
            for (int s = 0; s < 8; ++s)
                bw[s] = bin ? W[(size_t)(kb + bms * 8 + s) * LOW + n0 + bn] : 0.f;
        }
        #pragma unroll
        for (int ks = 0; ks < 2; ++ks) {
            const int ko = ks * 16 + lg * 4;
            U4V8 af; af.u = *(const uint4*)&As[buf][wm * 16 + lr][ko];
            U4V8 bf; bf.u = *(const uint4*)&Bs[buf][wn * 16 + lr][ko];
            acc = __builtin_amdgcn_mfma_f32_16x16x32_f16(af.v, bf.v, acc, 0, 0, 0);
        }
    }

    // D: col = l&15, row = 4*(l>>4)+r  (m89-verified)
    const int col = n0 + wn * 16 + lr;
    const float b1v = (which && col < LOW) ? b1g[col] : 0.f;
    #pragma unroll
    for (int r = 0; r < 4; ++r) {
        const int row = r0 + wm * 16 + lg * 4 + r;
        outh[(size_t)row * KP + col] = (_Float16)(acc[r] + b1v);
    }
}

// ---------------------------------------------------------------------------
// Kernel 2: pairwise critic, [row][k] natural LDS layout, 32i x 32j tile.
//   s[i][j] = sum_k relu(hy[i,k]+hx[j,k])*w2[k] + b2
//   partsum[i] += sum_j e^s  (exp(softplus)=1+e^s);  diag[i]=softplus(s[i,i])
// 256 thr, per-thread 2i x 2j x full-K. LDS 42.6 KB -> 3 blocks/CU
// (12 waves/CU, 3/SIMD). Staging = straight coalesced uint4 copies (no
// transpose). Inner loop: 5 x b128 LDS per 48 VALU, 8 k per read.
// Grid 1024 (32 ib x 32 jb); atomic finish (r12-verified, target 1023).
// ---------------------------------------------------------------------------
__global__ __launch_bounds__(256)
void pair_kernel(const unsigned int* __restrict__ hx_h, const unsigned int* __restrict__ hy_h,
                 const float* __restrict__ W2, const float* __restrict__ b2,
                 float* __restrict__ partsum, float* __restrict__ diag,
                 unsigned int* __restrict__ cnt, float* __restrict__ out)
{
    const int jb = blockIdx.x & 31, ib = blockIdx.x >> 5;
    const int j0 = jb * 32, i0 = ib * 32;

    __shared__ unsigned int Hy[32][164];   // [i][k/2], stride 164 u32
    __shared__ unsigned int Hx[32][164];   // [j][k/2]
    __shared__ uint4 w2q[40];              // 160 u32 of packed w2
    __shared__ unsigned int lastFlag;
    __shared__ float ssum[4];

    const int tid = threadIdx.x;

    // ---- stage (coalesced, no transpose): 5 uint4 per thread per matrix ----
    {
        const int r = tid >> 3, q = tid & 7;
        const unsigned int* sy = &hy_h[(size_t)(i0 + r) * KP2];
        const unsigned int* sx = &hx_h[(size_t)(j0 + r) * KP2];
        #pragma unroll
        for (int e = 0; e < 5; ++e) {
            const int c4 = (q + 8 * e) * 4;
            *(uint4*)&Hy[r][c4] = *(const uint4*)&sy[c4];
            *(uint4*)&Hx[r][c4] = *(const uint4*)&sx[c4];
        }
    }
    if (tid < 40) {
        const int k = tid * 8;                 // 8 k per uint4
        float wv[8];
        #pragma unroll
        for (int e = 0; e < 8; ++e)
            wv[e] = (k + e < LOW) ? W2[k + e] : 0.f;
        w2q[tid] = uint4{ pk(wv[0],wv[1]), pk(wv[2],wv[3]),
                          pk(wv[4],wv[5]), pk(wv[6],wv[7]) };
    }
    __syncthreads();

    const int tx = tid & 15;           // j pair: {j0+2tx, j0+2tx+1}
    const int ty = tid >> 4;           // i pair: {i0+2ty, i0+2ty+1}

    float a00 = 0.f, a01 = 0.f, a10 = 0.f, a11 = 0.f;
    const h2 hz = h2{(_Float16)0.f, (_Float16)0.f};

    #pragma unroll 4
    for (int t = 0; t < 40; ++t) {
        const uint4 ya0 = *(const uint4*)&Hy[2*ty  ][t*4];
        const uint4 ya1 = *(const uint4*)&Hy[2*ty+1][t*4];
        const uint4 xb0 = *(const uint4*)&Hx[2*tx  ][t*4];
        const uint4 xb1 = *(const uint4*)&Hx[2*tx+1][t*4];
        const uint4 wv  = w2q[t];
        const unsigned int y0e[4] = {ya0.x, ya0.y, ya0.z, ya0.w};
        const unsigned int y1e[4] = {ya1.x, ya1.y, ya1.z, ya1.w};
        const unsigned int x0e[4] = {xb0.x, xb0.y, xb0.z, xb0.w};
        const unsigned int x1e[4] = {xb1.x, xb1.y, xb1.z, xb1.w};
        const unsigned int wve[4] = {wv.x, wv.y, wv.z, wv.w};
        #pragma unroll
        for (int e = 0; e < 4; ++e) {
            const h2 w  = u2h(wve[e]);
            const h2 p0 = u2h(y0e[e]), p1 = u2h(y1e[e]);
            const h2 q0 = u2h(x0e[e]), q1 = u2h(x1e[e]);
            a00 = __builtin_amdgcn_fdot2(__builtin_elementwise_max(p0 + q0, hz), w, a00, false);
            a01 = __builtin_amdgcn_fdot2(__builtin_elementwise_max(p0 + q1, hz), w, a01, false);
            a10 = __builtin_amdgcn_fdot2(__builtin_elementwise_max(p1 + q0, hz), w, a10, false);
            a11 = __builtin_amdgcn_fdot2(__builtin_elementwise_max(p1 + q1, hz), w, a11, false);
        }
    }

    const float b2v = b2[0];
    const int row0 = i0 + 2*ty, row1 = row0 + 1;
    const int col0 = j0 + 2*tx, col1 = col0 + 1;
    const float s00 = a00 + b2v, s01 = a01 + b2v;
    const float s10 = a10 + b2v, s11 = a11 + b2v;

    if (col0 == row0) atomicExch(&diag[row0], fmaxf(s00,0.f) + __logf(1.f + __expf(-fabsf(s00))));
    if (col1 == row0) atomicExch(&diag[row0], fmaxf(s01,0.f) + __logf(1.f + __expf(-fabsf(s01))));
    if (col0 == row1) atomicExch(&diag[row1], fmaxf(s10,0.f) + __logf(1.f + __expf(-fabsf(s10))));
    if (col1 == row1) atomicExch(&diag[row1], fmaxf(s11,0.f) + __logf(1.f + __expf(-fabsf(s11))));

    float es0 = __expf(s00) + __expf(s01);     // exp(softplus) = 1+e^s
    float es1 = __expf(s10) + __expf(s11);
    #pragma unroll
    for (int o = 1; o <= 8; o <<= 1) {
        es0 += __shfl_xor(es0, o, 64);
        es1 += __shfl_xor(es1, o, 64);
    }
    if (tx == 0) {
        atomicAdd(&partsum[row0], es0);
        atomicAdd(&partsum[row1], es1);
    }

    // ---- completion: drain atomics, count blocks, last block reduces ----
    asm volatile("s_waitcnt vmcnt(0)" ::: "memory");
    __syncthreads();
    if (tid == 0) lastFlag = (atomicAdd(cnt, 1u) == 1023u) ? 1u : 0u;
    __syncthreads();
    if (!lastFlag) return;

    float csum = 0.f;
    #pragma unroll
    for (int g = 0; g < 4; ++g) {
        const int row = g * 256 + tid;
        const float ps = atomicAdd(&partsum[row], 0.f);   // coherent read
        const float dg = atomicAdd(&diag[row], 0.f);      // coherent read
        csum += dg - __logf((float)N_S + ps);
    }
    #pragma unroll
    for (int o = 32; o > 0; o >>= 1) csum += __shfl_xor(csum, o, 64);
    if ((tid & 63) == 0) ssum[tid >> 6] = csum;
    __syncthreads();
    if (tid == 0)
        out[0] = (ssum[0] + ssum[1] + ssum[2] + ssum[3]) * (1.0f / N_S)
               - logf((float)N_S);
}

// ---------------------------------------------------------------------------
extern "C" void kernel_launch(void* const* d_in, const int* in_sizes, int n_in,
                              void* d_out, int out_size, void* d_ws, size_t ws_size,
                              hipStream_t stream)
{
    const float* x  = (const float*)d_in[0];
    const float* y  = (const float*)d_in[1];
    const float* W1 = (const float*)d_in[2];
    const float* b1 = (const float*)d_in[3];
    const float* W2 = (const float*)d_in[4];
    const float* b2 = (const float*)d_in[5];
    float* outp = (float*)d_out;

    unsigned int* hx_h = (unsigned int*)d_ws;             // N_S*KP2 u32
    unsigned int* hy_h = hx_h + (size_t)N_S * KP2;        // N_S*KP2 u32
    float* partsum = (float*)(hy_h + (size_t)N_S * KP2);  // N_S f32
    float* diag = partsum + N_S;                          // N_S f32
    unsigned int* cnt = (unsigned int*)(diag + N_S);      // 1 u32

    gemm_h<<<320, 512, 0, stream>>>(x, y, W1, b1, hx_h, hy_h, partsum, cnt);

    pair_kernel<<<1024, 256, 0, stream>>>(hx_h, hy_h, W2, b2,
                                          partsum, diag, cnt, outp);
}